// Round 1
// baseline (4568.134 us; speedup 1.0000x reference)
//
#include <hip/hip_runtime.h>

#define N_NODES 500000
#define N_EDGES 8000000
#define FEAT 10
#define HID 32
#define N_TOOLS 13
#define N_PRIM 8

// ---------------------------------------------------------------------------
// Kernel 1: edge scatter — agg[dst] += x[src], cnt[dst] += 1
// ---------------------------------------------------------------------------
__global__ void scatter_kernel(const int* __restrict__ src,
                               const int* __restrict__ dst,
                               const float* __restrict__ x,
                               float* __restrict__ agg,
                               float* __restrict__ cnt) {
    int e = blockIdx.x * blockDim.x + threadIdx.x;
    if (e >= N_EDGES) return;
    int s = src[e];
    int d = dst[e];
    const float* xr = x + (size_t)s * FEAT;
    float* ar = agg + (size_t)d * FEAT;
#pragma unroll
    for (int k = 0; k < FEAT; ++k) {
        atomicAdd(&ar[k], xr[k]);
    }
    atomicAdd(&cnt[d], 1.0f);
}

// ---------------------------------------------------------------------------
// Kernel 2: per-(node, j) h = relu(x@w_self + b_self + (agg/cnt)@w_neigh + b_neigh)
// Each thread owns a fixed output column j = tid & 31 (weights in registers),
// grid-strides over nodes. Also accumulates the graph-embed partial sum.
// ---------------------------------------------------------------------------
__global__ void node_kernel(const float* __restrict__ x,
                            const float* __restrict__ agg,
                            const float* __restrict__ cnt,
                            const float* __restrict__ w_self,
                            const float* __restrict__ b_self,
                            const float* __restrict__ w_neigh,
                            const float* __restrict__ b_neigh,
                            float* __restrict__ h_out,   // d_out + 53
                            float* __restrict__ hsum) {  // 32 floats (zeroed)
    const int j = threadIdx.x & 31;   // stride is a multiple of 32 -> invariant
    float ws[FEAT], wn[FEAT];
#pragma unroll
    for (int k = 0; k < FEAT; ++k) {
        ws[k] = w_self[k * HID + j];
        wn[k] = w_neigh[k * HID + j];
    }
    const float bias = b_self[j] + b_neigh[j];

    const long total = (long)N_NODES * HID;
    const long stride = (long)gridDim.x * blockDim.x;
    float partial = 0.0f;
    for (long idx = (long)blockIdx.x * blockDim.x + threadIdx.x; idx < total;
         idx += stride) {
        const int i = (int)(idx >> 5);  // node index; idx & 31 == j
        const float inv = 1.0f / fmaxf(cnt[i], 1.0f);
        const float* xr = x + (size_t)i * FEAT;
        const float* ar = agg + (size_t)i * FEAT;
        float acc = bias;
#pragma unroll
        for (int k = 0; k < FEAT; ++k) {
            acc += xr[k] * ws[k];
            acc += (ar[k] * inv) * wn[k];
        }
        acc = fmaxf(acc, 0.0f);
        h_out[idx] = acc;
        partial += acc;
    }

    // Reduce partial sums: lanes L and L+32 share the same j.
    partial += __shfl_down(partial, 32);
    __shared__ float red[4][HID];  // blockDim.x == 256 -> 4 waves
    const int wave = threadIdx.x >> 6;
    const int lane = threadIdx.x & 63;
    if (lane < 32) red[wave][lane] = partial;
    __syncthreads();
    if (threadIdx.x < 32) {
        float s = red[0][threadIdx.x] + red[1][threadIdx.x] +
                  red[2][threadIdx.x] + red[3][threadIdx.x];
        atomicAdd(&hsum[threadIdx.x], s);
    }
}

// ---------------------------------------------------------------------------
// Kernel 3: graph_embed = hsum / N; the two logit heads.
// ---------------------------------------------------------------------------
__global__ void head_kernel(const float* __restrict__ hsum,
                            const float* __restrict__ w_act,
                            const float* __restrict__ b_act,
                            const float* __restrict__ w_prim,
                            const float* __restrict__ b_prim,
                            float* __restrict__ out) {
    __shared__ float ge[HID];
    const int t = threadIdx.x;
    if (t < HID) {
        const float g = hsum[t] * (1.0f / (float)N_NODES);
        ge[t] = g;
        out[N_TOOLS + N_PRIM + t] = g;  // graph_embed at offset 21
    }
    __syncthreads();
    if (t < N_TOOLS) {
        float a = b_act[t];
#pragma unroll
        for (int jj = 0; jj < HID; ++jj) a += ge[jj] * w_act[jj * N_TOOLS + t];
        out[t] = a;  // action_logits at offset 0
    }
    if (t >= 32 && t < 32 + N_PRIM) {
        const int p = t - 32;
        float a = b_prim[p];
#pragma unroll
        for (int jj = 0; jj < HID; ++jj) a += ge[jj] * w_prim[jj * N_PRIM + p];
        out[N_TOOLS + p] = a;  // primitive_logits at offset 13
    }
}

extern "C" void kernel_launch(void* const* d_in, const int* in_sizes, int n_in,
                              void* d_out, int out_size, void* d_ws,
                              size_t ws_size, hipStream_t stream) {
    const float* x       = (const float*)d_in[0];
    const int*   ei      = (const int*)d_in[1];  // [2, N_EDGES] row-major int32
    const float* w_self  = (const float*)d_in[2];
    const float* b_self  = (const float*)d_in[3];
    const float* w_neigh = (const float*)d_in[4];
    const float* b_neigh = (const float*)d_in[5];
    const float* w_act   = (const float*)d_in[6];
    const float* b_act   = (const float*)d_in[7];
    const float* w_prim  = (const float*)d_in[8];
    const float* b_prim  = (const float*)d_in[9];
    float* out = (float*)d_out;

    // Workspace layout: agg [N*FEAT] | cnt [N] | hsum [HID]
    float* agg  = (float*)d_ws;
    float* cnt  = agg + (size_t)N_NODES * FEAT;
    float* hsum = cnt + N_NODES;
    const size_t zero_bytes =
        ((size_t)N_NODES * FEAT + N_NODES + HID) * sizeof(float);
    hipMemsetAsync(d_ws, 0, zero_bytes, stream);

    scatter_kernel<<<(N_EDGES + 255) / 256, 256, 0, stream>>>(
        ei, ei + N_EDGES, x, agg, cnt);

    node_kernel<<<4096, 256, 0, stream>>>(x, agg, cnt, w_self, b_self, w_neigh,
                                          b_neigh, out + (N_TOOLS + N_PRIM + HID),
                                          hsum);

    head_kernel<<<1, 64, 0, stream>>>(hsum, w_act, b_act, w_prim, b_prim, out);
}

// Round 2
// 1249.079 us; speedup vs baseline: 3.6572x; 3.6572x over previous
//
#include <hip/hip_runtime.h>

#define N_NODES 500000
#define N_EDGES 8000000
#define FEAT 10
#define HID 32
#define N_TOOLS 13
#define N_PRIM 8

#define SCAN_TILE 1024
#define N_TILES ((N_NODES + SCAN_TILE - 1) / SCAN_TILE)  // 489

// ===========================================================================
// Counting-sort path
// ===========================================================================

// ---- hist: cnt_i[dst]++ over all edges --------------------------------------
__global__ void hist_kernel(const int* __restrict__ dst, int* __restrict__ cnt_i) {
    int e = blockIdx.x * blockDim.x + threadIdx.x;
    if (e >= N_EDGES) return;
    atomicAdd(&cnt_i[dst[e]], 1);
}

// ---- scan step 1: per-tile (1024) sums -------------------------------------
__global__ void scan1_kernel(const int* __restrict__ cnt_i, int* __restrict__ bsum) {
    const int b = blockIdx.x;
    const int t = threadIdx.x;  // 256 threads, 4 elems each
    int s = 0;
#pragma unroll
    for (int k = 0; k < 4; ++k) {
        int idx = b * SCAN_TILE + t * 4 + k;
        if (idx < N_NODES) s += cnt_i[idx];
    }
    // wave reduce (64 lanes)
    for (int off = 32; off > 0; off >>= 1) s += __shfl_down(s, off);
    __shared__ int red[4];
    if ((t & 63) == 0) red[t >> 6] = s;
    __syncthreads();
    if (t == 0) bsum[b] = red[0] + red[1] + red[2] + red[3];
}

// ---- scan step 2: exclusive scan of the 489 tile sums (serial, tiny) -------
__global__ void scan2_kernel(int* __restrict__ bsum) {
    if (threadIdx.x == 0 && blockIdx.x == 0) {
        int run = 0;
        for (int i = 0; i < N_TILES; ++i) {
            int t = bsum[i];
            bsum[i] = run;
            run += t;
        }
    }
}

// ---- scan step 3: per-tile exclusive offsets -> off[] ----------------------
__global__ void scan3_kernel(const int* __restrict__ cnt_i,
                             const int* __restrict__ bsum,
                             int* __restrict__ off) {
    const int b = blockIdx.x;
    const int t = threadIdx.x;
    int v[4];
    int s = 0;
#pragma unroll
    for (int k = 0; k < 4; ++k) {
        int idx = b * SCAN_TILE + t * 4 + k;
        v[k] = (idx < N_NODES) ? cnt_i[idx] : 0;
        s += v[k];
    }
    __shared__ int lds[256];
    lds[t] = s;
    __syncthreads();
    if (t == 0) {  // serial exclusive scan of 256 thread-sums
        int run = 0;
        for (int i = 0; i < 256; ++i) {
            int x = lds[i];
            lds[i] = run;
            run += x;
        }
    }
    __syncthreads();
    int run = bsum[b] + lds[t];
#pragma unroll
    for (int k = 0; k < 4; ++k) {
        int idx = b * SCAN_TILE + t * 4 + k;
        if (idx < N_NODES) off[idx] = run;
        run += v[k];
    }
}

// ---- reorder: order[atomic(off[dst])++] = src ------------------------------
// After this pass, off[d] == END of segment d (start = off[d-1], d>0 else 0).
__global__ void reorder_kernel(const int* __restrict__ src,
                               const int* __restrict__ dst,
                               int* __restrict__ off,
                               int* __restrict__ order) {
    int e = blockIdx.x * blockDim.x + threadIdx.x;
    if (e >= N_EDGES) return;
    int s = src[e];
    int d = dst[e];
    int pos = atomicAdd(&off[d], 1);
    order[pos] = s;
}

// ---- gather-reduce: agg[i] = sum over segment of x[order[o]]; cntf[i]=deg --
__global__ void gather_kernel(const int* __restrict__ off,
                              const int* __restrict__ order,
                              const float* __restrict__ x,
                              float* __restrict__ agg,
                              float* __restrict__ cntf) {
    int i = blockIdx.x * blockDim.x + threadIdx.x;
    if (i >= N_NODES) return;
    int start = (i > 0) ? off[i - 1] : 0;
    int end = off[i];
    float a[FEAT];
#pragma unroll
    for (int k = 0; k < FEAT; ++k) a[k] = 0.0f;
    for (int o = start; o < end; ++o) {
        const float* xr = x + (size_t)order[o] * FEAT;
#pragma unroll
        for (int k = 0; k < FEAT; ++k) a[k] += xr[k];
    }
    float* ar = agg + (size_t)i * FEAT;
#pragma unroll
    for (int k = 0; k < FEAT; ++k) ar[k] = a[k];
    cntf[i] = (float)(end - start);
}

// ===========================================================================
// Fallback path (round-1 atomic scatter) — used only if ws_size is too small
// ===========================================================================
__global__ void scatter_kernel(const int* __restrict__ src,
                               const int* __restrict__ dst,
                               const float* __restrict__ x,
                               float* __restrict__ agg,
                               float* __restrict__ cnt) {
    int e = blockIdx.x * blockDim.x + threadIdx.x;
    if (e >= N_EDGES) return;
    int s = src[e];
    int d = dst[e];
    const float* xr = x + (size_t)s * FEAT;
    float* ar = agg + (size_t)d * FEAT;
#pragma unroll
    for (int k = 0; k < FEAT; ++k) atomicAdd(&ar[k], xr[k]);
    atomicAdd(&cnt[d], 1.0f);
}

// ===========================================================================
// Node transform + fused graph-embed partial reduction (unchanged, working)
// ===========================================================================
__global__ void node_kernel(const float* __restrict__ x,
                            const float* __restrict__ agg,
                            const float* __restrict__ cnt,
                            const float* __restrict__ w_self,
                            const float* __restrict__ b_self,
                            const float* __restrict__ w_neigh,
                            const float* __restrict__ b_neigh,
                            float* __restrict__ h_out,
                            float* __restrict__ hsum) {
    const int j = threadIdx.x & 31;
    float ws[FEAT], wn[FEAT];
#pragma unroll
    for (int k = 0; k < FEAT; ++k) {
        ws[k] = w_self[k * HID + j];
        wn[k] = w_neigh[k * HID + j];
    }
    const float bias = b_self[j] + b_neigh[j];

    const long total = (long)N_NODES * HID;
    const long stride = (long)gridDim.x * blockDim.x;
    float partial = 0.0f;
    for (long idx = (long)blockIdx.x * blockDim.x + threadIdx.x; idx < total;
         idx += stride) {
        const int i = (int)(idx >> 5);
        const float inv = 1.0f / fmaxf(cnt[i], 1.0f);
        const float* xr = x + (size_t)i * FEAT;
        const float* ar = agg + (size_t)i * FEAT;
        float acc = bias;
#pragma unroll
        for (int k = 0; k < FEAT; ++k) {
            acc += xr[k] * ws[k];
            acc += (ar[k] * inv) * wn[k];
        }
        acc = fmaxf(acc, 0.0f);
        h_out[idx] = acc;
        partial += acc;
    }

    partial += __shfl_down(partial, 32);
    __shared__ float red[4][HID];
    const int wave = threadIdx.x >> 6;
    const int lane = threadIdx.x & 63;
    if (lane < 32) red[wave][lane] = partial;
    __syncthreads();
    if (threadIdx.x < 32) {
        float s = red[0][threadIdx.x] + red[1][threadIdx.x] +
                  red[2][threadIdx.x] + red[3][threadIdx.x];
        atomicAdd(&hsum[threadIdx.x], s);
    }
}

__global__ void head_kernel(const float* __restrict__ hsum,
                            const float* __restrict__ w_act,
                            const float* __restrict__ b_act,
                            const float* __restrict__ w_prim,
                            const float* __restrict__ b_prim,
                            float* __restrict__ out) {
    __shared__ float ge[HID];
    const int t = threadIdx.x;
    if (t < HID) {
        const float g = hsum[t] * (1.0f / (float)N_NODES);
        ge[t] = g;
        out[N_TOOLS + N_PRIM + t] = g;
    }
    __syncthreads();
    if (t < N_TOOLS) {
        float a = b_act[t];
#pragma unroll
        for (int jj = 0; jj < HID; ++jj) a += ge[jj] * w_act[jj * N_TOOLS + t];
        out[t] = a;
    }
    if (t >= 32 && t < 32 + N_PRIM) {
        const int p = t - 32;
        float a = b_prim[p];
#pragma unroll
        for (int jj = 0; jj < HID; ++jj) a += ge[jj] * w_prim[jj * N_PRIM + p];
        out[N_TOOLS + p] = a;
    }
}

extern "C" void kernel_launch(void* const* d_in, const int* in_sizes, int n_in,
                              void* d_out, int out_size, void* d_ws,
                              size_t ws_size, hipStream_t stream) {
    const float* x       = (const float*)d_in[0];
    const int*   ei      = (const int*)d_in[1];
    const float* w_self  = (const float*)d_in[2];
    const float* b_self  = (const float*)d_in[3];
    const float* w_neigh = (const float*)d_in[4];
    const float* b_neigh = (const float*)d_in[5];
    const float* w_act   = (const float*)d_in[6];
    const float* b_act   = (const float*)d_in[7];
    const float* w_prim  = (const float*)d_in[8];
    const float* b_prim  = (const float*)d_in[9];
    float* out = (float*)d_out;
    const int* src = ei;
    const int* dst = ei + N_EDGES;

    // Counting-sort workspace layout (all 4-byte elems):
    //   [cnt_i N][hsum 32][bsum N_TILES][off N][cntf N][agg N*FEAT][order E]
    const size_t n_cnt   = N_NODES;
    const size_t n_hsum  = HID;
    const size_t n_bsum  = N_TILES;
    const size_t n_off   = N_NODES;
    const size_t n_cntf  = N_NODES;
    const size_t n_agg   = (size_t)N_NODES * FEAT;
    const size_t n_order = N_EDGES;
    const size_t need =
        (n_cnt + n_hsum + n_bsum + n_off + n_cntf + n_agg + n_order) * 4;

    if (ws_size >= need) {
        int*   cnt_i = (int*)d_ws;
        float* hsum  = (float*)(cnt_i + n_cnt);
        int*   bsum  = (int*)(hsum + n_hsum);
        int*   off   = bsum + n_bsum;
        float* cntf  = (float*)(off + n_off);
        float* agg   = cntf + n_cntf;
        int*   order = (int*)(agg + n_agg);

        // zero only what needs zeroing: cnt_i + hsum (adjacent)
        hipMemsetAsync(d_ws, 0, (n_cnt + n_hsum) * 4, stream);

        hist_kernel<<<(N_EDGES + 255) / 256, 256, 0, stream>>>(dst, cnt_i);
        scan1_kernel<<<N_TILES, 256, 0, stream>>>(cnt_i, bsum);
        scan2_kernel<<<1, 64, 0, stream>>>(bsum);
        scan3_kernel<<<N_TILES, 256, 0, stream>>>(cnt_i, bsum, off);
        reorder_kernel<<<(N_EDGES + 255) / 256, 256, 0, stream>>>(src, dst, off,
                                                                  order);
        gather_kernel<<<(N_NODES + 255) / 256, 256, 0, stream>>>(off, order, x,
                                                                 agg, cntf);
        node_kernel<<<4096, 256, 0, stream>>>(
            x, agg, cntf, w_self, b_self, w_neigh, b_neigh,
            out + (N_TOOLS + N_PRIM + HID), hsum);
        head_kernel<<<1, 64, 0, stream>>>(hsum, w_act, b_act, w_prim, b_prim,
                                          out);
    } else {
        // Fallback: round-1 atomic scatter (needs ~22 MB)
        float* agg  = (float*)d_ws;
        float* cnt  = agg + (size_t)N_NODES * FEAT;
        float* hsum = cnt + N_NODES;
        const size_t zero_bytes =
            ((size_t)N_NODES * FEAT + N_NODES + HID) * sizeof(float);
        hipMemsetAsync(d_ws, 0, zero_bytes, stream);

        scatter_kernel<<<(N_EDGES + 255) / 256, 256, 0, stream>>>(src, dst, x,
                                                                  agg, cnt);
        node_kernel<<<4096, 256, 0, stream>>>(
            x, agg, cnt, w_self, b_self, w_neigh, b_neigh,
            out + (N_TOOLS + N_PRIM + HID), hsum);
        head_kernel<<<1, 64, 0, stream>>>(hsum, w_act, b_act, w_prim, b_prim,
                                          out);
    }
}

// Round 3
// 829.833 us; speedup vs baseline: 5.5049x; 1.5052x over previous
//
#include <hip/hip_runtime.h>

#define N_NODES 500000
#define N_EDGES 8000000
#define FEAT 10
#define HID 32
#define N_TOOLS 13
#define N_PRIM 8

// ---- bucketing geometry ----------------------------------------------------
#define BK_BITS 10
#define BK_SIZE (1 << BK_BITS)                        // 1024 nodes / bucket
#define NB ((N_NODES + BK_SIZE - 1) / BK_SIZE)        // 489 buckets
#define SC_THREADS 512
#define SC_EPT 16
#define SC_CHUNK (SC_THREADS * SC_EPT)                // 8192 edges / block
#define SC_BLOCKS ((N_EDGES + SC_CHUNK - 1) / SC_CHUNK)  // 977

// ===========================================================================
// 1) per-block bucket histogram (LDS only, no global atomics)
// ===========================================================================
__global__ __launch_bounds__(SC_THREADS) void bhist_kernel(
    const int* __restrict__ dst, int* __restrict__ bhist) {
    __shared__ int hist[NB];
    const int t = threadIdx.x;
    for (int i = t; i < NB; i += SC_THREADS) hist[i] = 0;
    __syncthreads();
    const int base = blockIdx.x * SC_CHUNK;
#pragma unroll
    for (int k = 0; k < SC_EPT; ++k) {
        int e = base + k * SC_THREADS + t;  // coalesced
        if (e < N_EDGES) atomicAdd(&hist[dst[e] >> BK_BITS], 1);
    }
    __syncthreads();
    int* row = bhist + (size_t)blockIdx.x * NB;
    for (int i = t; i < NB; i += SC_THREADS) row[i] = hist[i];
}

// ===========================================================================
// 2) exclusive scan: bucket starts + per-(block,bucket) exact offsets
// ===========================================================================
__global__ __launch_bounds__(SC_THREADS) void bscan_kernel(
    int* __restrict__ bhist, int* __restrict__ bstart) {
    __shared__ int col[NB];
    const int t = threadIdx.x;
    if (t < NB) {
        int s = 0;
        for (int r = 0; r < SC_BLOCKS; ++r) s += bhist[(size_t)r * NB + t];
        col[t] = s;
    }
    __syncthreads();
    if (t == 0) {
        int run = 0;
        for (int i = 0; i < NB; ++i) {
            int c = col[i];
            col[i] = run;
            bstart[i] = run;
            run += c;
        }
        bstart[NB] = run;  // == N_EDGES
    }
    __syncthreads();
    if (t < NB) {
        int run = col[t];
        for (int r = 0; r < SC_BLOCKS; ++r) {  // coalesced across t
            size_t idx = (size_t)r * NB + t;
            int c = bhist[idx];
            bhist[idx] = run;
            run += c;
        }
    }
}

// ===========================================================================
// 3) multisplit scatter: store[offset] = (local_dst<<19)|src  (deterministic)
// ===========================================================================
__global__ __launch_bounds__(SC_THREADS) void mscatter_kernel(
    const int* __restrict__ src, const int* __restrict__ dst,
    const int* __restrict__ bhist, int* __restrict__ store) {
    __shared__ int hist[NB];
    __shared__ int basel[NB];
    const int t = threadIdx.x;
    for (int i = t; i < NB; i += SC_THREADS) hist[i] = 0;
    __syncthreads();
    const int base = blockIdx.x * SC_CHUNK;
    int bkt[SC_EPT], rnk[SC_EPT], pkd[SC_EPT];
#pragma unroll
    for (int k = 0; k < SC_EPT; ++k) {
        int e = base + k * SC_THREADS + t;
        bkt[k] = -1;
        if (e < N_EDGES) {
            int d = dst[e];
            int s = src[e];
            bkt[k] = d >> BK_BITS;
            pkd[k] = ((d & (BK_SIZE - 1)) << 19) | s;  // src < 2^19
            rnk[k] = atomicAdd(&hist[bkt[k]], 1);      // LDS atomic, rank
        }
    }
    __syncthreads();
    const int* row = bhist + (size_t)blockIdx.x * NB;
    for (int i = t; i < NB; i += SC_THREADS) basel[i] = row[i];
    __syncthreads();
#pragma unroll
    for (int k = 0; k < SC_EPT; ++k) {
        if (bkt[k] >= 0) store[basel[bkt[k]] + rnk[k]] = pkd[k];
    }
}

// ===========================================================================
// 4) per-bucket LDS aggregation: agg slice + count slice, no global atomics
// ===========================================================================
__global__ __launch_bounds__(256) void baggr_kernel(
    const int* __restrict__ bstart, const int* __restrict__ store,
    const float* __restrict__ x, float* __restrict__ agg,
    float* __restrict__ cntf) {
    __shared__ float lagg[BK_SIZE * FEAT];  // 40 KB
    __shared__ float lcnt[BK_SIZE];         // 4 KB
    const int t = threadIdx.x;
    const int b = blockIdx.x;
    for (int i = t; i < BK_SIZE * FEAT; i += 256) lagg[i] = 0.0f;
    for (int i = t; i < BK_SIZE; i += 256) lcnt[i] = 0.0f;
    __syncthreads();
    const int s0 = bstart[b], e0 = bstart[b + 1];
    for (int o = s0 + t; o < e0; o += 256) {
        int v = store[o];                       // coalesced
        int s = v & 0x7FFFF;
        int loc = v >> 19;                      // 0..1023
        const float2* xr = (const float2*)(x + (size_t)s * FEAT);  // 8B aligned
        float2 p0 = xr[0], p1 = xr[1], p2 = xr[2], p3 = xr[3], p4 = xr[4];
        float* la = lagg + loc * FEAT;
        atomicAdd(&la[0], p0.x); atomicAdd(&la[1], p0.y);
        atomicAdd(&la[2], p1.x); atomicAdd(&la[3], p1.y);
        atomicAdd(&la[4], p2.x); atomicAdd(&la[5], p2.y);
        atomicAdd(&la[6], p3.x); atomicAdd(&la[7], p3.y);
        atomicAdd(&la[8], p4.x); atomicAdd(&la[9], p4.y);
        atomicAdd(&lcnt[loc], 1.0f);
    }
    __syncthreads();
    const int node0 = b << BK_BITS;
    float* ag = agg + (size_t)node0 * FEAT;
    const int lim = (N_NODES - node0 < BK_SIZE ? N_NODES - node0 : BK_SIZE);
    for (int i = t; i < lim * FEAT; i += 256) ag[i] = lagg[i];
    for (int i = t; i < lim; i += 256) cntf[node0 + i] = lcnt[i];
}

// ===========================================================================
// node transform + fused graph-embed partial reduction (unchanged)
// ===========================================================================
__global__ void node_kernel(const float* __restrict__ x,
                            const float* __restrict__ agg,
                            const float* __restrict__ cnt,
                            const float* __restrict__ w_self,
                            const float* __restrict__ b_self,
                            const float* __restrict__ w_neigh,
                            const float* __restrict__ b_neigh,
                            float* __restrict__ h_out,
                            float* __restrict__ hsum) {
    const int j = threadIdx.x & 31;
    float ws[FEAT], wn[FEAT];
#pragma unroll
    for (int k = 0; k < FEAT; ++k) {
        ws[k] = w_self[k * HID + j];
        wn[k] = w_neigh[k * HID + j];
    }
    const float bias = b_self[j] + b_neigh[j];

    const long total = (long)N_NODES * HID;
    const long stride = (long)gridDim.x * blockDim.x;
    float partial = 0.0f;
    for (long idx = (long)blockIdx.x * blockDim.x + threadIdx.x; idx < total;
         idx += stride) {
        const int i = (int)(idx >> 5);
        const float inv = 1.0f / fmaxf(cnt[i], 1.0f);
        const float* xr = x + (size_t)i * FEAT;
        const float* ar = agg + (size_t)i * FEAT;
        float acc = bias;
#pragma unroll
        for (int k = 0; k < FEAT; ++k) {
            acc += xr[k] * ws[k];
            acc += (ar[k] * inv) * wn[k];
        }
        acc = fmaxf(acc, 0.0f);
        h_out[idx] = acc;
        partial += acc;
    }

    partial += __shfl_down(partial, 32);
    __shared__ float red[4][HID];
    const int wave = threadIdx.x >> 6;
    const int lane = threadIdx.x & 63;
    if (lane < 32) red[wave][lane] = partial;
    __syncthreads();
    if (threadIdx.x < 32) {
        float s = red[0][threadIdx.x] + red[1][threadIdx.x] +
                  red[2][threadIdx.x] + red[3][threadIdx.x];
        atomicAdd(&hsum[threadIdx.x], s);
    }
}

__global__ void head_kernel(const float* __restrict__ hsum,
                            const float* __restrict__ w_act,
                            const float* __restrict__ b_act,
                            const float* __restrict__ w_prim,
                            const float* __restrict__ b_prim,
                            float* __restrict__ out) {
    __shared__ float ge[HID];
    const int t = threadIdx.x;
    if (t < HID) {
        const float g = hsum[t] * (1.0f / (float)N_NODES);
        ge[t] = g;
        out[N_TOOLS + N_PRIM + t] = g;
    }
    __syncthreads();
    if (t < N_TOOLS) {
        float a = b_act[t];
#pragma unroll
        for (int jj = 0; jj < HID; ++jj) a += ge[jj] * w_act[jj * N_TOOLS + t];
        out[t] = a;
    }
    if (t >= 32 && t < 32 + N_PRIM) {
        const int p = t - 32;
        float a = b_prim[p];
#pragma unroll
        for (int jj = 0; jj < HID; ++jj) a += ge[jj] * w_prim[jj * N_PRIM + p];
        out[N_TOOLS + p] = a;
    }
}

// ===========================================================================
// fallback (round-1 atomic scatter), used only if ws_size is tiny
// ===========================================================================
__global__ void scatter_kernel(const int* __restrict__ src,
                               const int* __restrict__ dst,
                               const float* __restrict__ x,
                               float* __restrict__ agg,
                               float* __restrict__ cnt) {
    int e = blockIdx.x * blockDim.x + threadIdx.x;
    if (e >= N_EDGES) return;
    int s = src[e];
    int d = dst[e];
    const float* xr = x + (size_t)s * FEAT;
    float* ar = agg + (size_t)d * FEAT;
#pragma unroll
    for (int k = 0; k < FEAT; ++k) atomicAdd(&ar[k], xr[k]);
    atomicAdd(&cnt[d], 1.0f);
}

extern "C" void kernel_launch(void* const* d_in, const int* in_sizes, int n_in,
                              void* d_out, int out_size, void* d_ws,
                              size_t ws_size, hipStream_t stream) {
    const float* x       = (const float*)d_in[0];
    const int*   ei      = (const int*)d_in[1];
    const float* w_self  = (const float*)d_in[2];
    const float* b_self  = (const float*)d_in[3];
    const float* w_neigh = (const float*)d_in[4];
    const float* b_neigh = (const float*)d_in[5];
    const float* w_act   = (const float*)d_in[6];
    const float* b_act   = (const float*)d_in[7];
    const float* w_prim  = (const float*)d_in[8];
    const float* b_prim  = (const float*)d_in[9];
    float* out = (float*)d_out;
    const int* src = ei;
    const int* dst = ei + N_EDGES;

    // ws layout (ints/floats, 4B each):
    //   bhist [SC_BLOCKS*NB] | bstart [NB+1] | store [E] | agg [N*FEAT]
    //   | cntf [N] | hsum [HID]
    const size_t n_bhist = (size_t)SC_BLOCKS * NB;
    const size_t n_bst   = NB + 1;
    const size_t need =
        (n_bhist + n_bst + (size_t)N_EDGES + (size_t)N_NODES * FEAT + N_NODES +
         HID) * 4;

    if (ws_size >= need) {
        int*   bhist  = (int*)d_ws;
        int*   bstart = bhist + n_bhist;
        int*   store  = bstart + n_bst;
        float* agg    = (float*)(store + N_EDGES);
        float* cntf   = agg + (size_t)N_NODES * FEAT;
        float* hsum   = cntf + N_NODES;

        hipMemsetAsync(hsum, 0, HID * sizeof(float), stream);

        bhist_kernel<<<SC_BLOCKS, SC_THREADS, 0, stream>>>(dst, bhist);
        bscan_kernel<<<1, SC_THREADS, 0, stream>>>(bhist, bstart);
        mscatter_kernel<<<SC_BLOCKS, SC_THREADS, 0, stream>>>(src, dst, bhist,
                                                              store);
        baggr_kernel<<<NB, 256, 0, stream>>>(bstart, store, x, agg, cntf);
        node_kernel<<<4096, 256, 0, stream>>>(
            x, agg, cntf, w_self, b_self, w_neigh, b_neigh,
            out + (N_TOOLS + N_PRIM + HID), hsum);
        head_kernel<<<1, 64, 0, stream>>>(hsum, w_act, b_act, w_prim, b_prim,
                                          out);
    } else {
        float* agg  = (float*)d_ws;
        float* cnt  = agg + (size_t)N_NODES * FEAT;
        float* hsum = cnt + N_NODES;
        const size_t zero_bytes =
            ((size_t)N_NODES * FEAT + N_NODES + HID) * sizeof(float);
        hipMemsetAsync(d_ws, 0, zero_bytes, stream);

        scatter_kernel<<<(N_EDGES + 255) / 256, 256, 0, stream>>>(src, dst, x,
                                                                  agg, cnt);
        node_kernel<<<4096, 256, 0, stream>>>(
            x, agg, cnt, w_self, b_self, w_neigh, b_neigh,
            out + (N_TOOLS + N_PRIM + HID), hsum);
        head_kernel<<<1, 64, 0, stream>>>(hsum, w_act, b_act, w_prim, b_prim,
                                          out);
    }
}

// Round 4
// 814.851 us; speedup vs baseline: 5.6061x; 1.0184x over previous
//
#include <hip/hip_runtime.h>

#define N_NODES 500000
#define N_EDGES 8000000
#define FEAT 10
#define HID 32
#define N_TOOLS 13
#define N_PRIM 8

// ---- bucketing geometry ----------------------------------------------------
#define BK_BITS 8
#define BK_SIZE (1 << BK_BITS)                        // 256 nodes / bucket
#define NB ((N_NODES + BK_SIZE - 1) / BK_SIZE)        // 1954 buckets
#define SC_THREADS 512
#define SC_EPT 16
#define SC_CHUNK (SC_THREADS * SC_EPT)                // 8192 edges / block
#define SC_BLOCKS ((N_EDGES + SC_CHUNK - 1) / SC_CHUNK)  // 977
#define R_CH 8
#define ROWS_PER_CH ((SC_BLOCKS + R_CH - 1) / R_CH)   // 123

// ===========================================================================
// 1) per-block bucket histogram (LDS only, no global atomics)
// ===========================================================================
__global__ __launch_bounds__(SC_THREADS) void bhist_kernel(
    const int* __restrict__ dst, int* __restrict__ bhist) {
    __shared__ int hist[NB];
    const int t = threadIdx.x;
    for (int i = t; i < NB; i += SC_THREADS) hist[i] = 0;
    __syncthreads();
    const int base = blockIdx.x * SC_CHUNK;
#pragma unroll
    for (int k = 0; k < SC_EPT; ++k) {
        int e = base + k * SC_THREADS + t;  // coalesced
        if (e < N_EDGES) atomicAdd(&hist[dst[e] >> BK_BITS], 1);
    }
    __syncthreads();
    int* row = bhist + (size_t)blockIdx.x * NB;
    for (int i = t; i < NB; i += SC_THREADS) row[i] = hist[i];
}

// ===========================================================================
// 2a) column partial sums over row chunks: ctmp[rc][c]
// ===========================================================================
__global__ __launch_bounds__(256) void scan_a_kernel(
    const int* __restrict__ bhist, int* __restrict__ ctmp) {
    const int rc = blockIdx.x >> 3;
    const int cc = blockIdx.x & 7;
    const int c = cc * 256 + threadIdx.x;
    if (c >= NB) return;
    const int r0 = rc * ROWS_PER_CH;
    const int r1 = (r0 + ROWS_PER_CH < SC_BLOCKS) ? r0 + ROWS_PER_CH : SC_BLOCKS;
    int s = 0;
    for (int r = r0; r < r1; ++r) s += bhist[(size_t)r * NB + c];  // coalesced
    ctmp[rc * NB + c] = s;
}

// ===========================================================================
// 2b) bucket starts (exclusive scan of column totals) + per-chunk starts
// ===========================================================================
__global__ __launch_bounds__(256) void scan_b_kernel(
    const int* __restrict__ ctmp, int* __restrict__ bstart,
    int* __restrict__ cstart) {
    __shared__ int colt[NB];  // 7.8 KB
    const int t = threadIdx.x;
    for (int c = t; c < NB; c += 256) {
        int s = 0;
#pragma unroll
        for (int rc = 0; rc < R_CH; ++rc) s += ctmp[rc * NB + c];
        colt[c] = s;
    }
    __syncthreads();
    if (t == 0) {
        int run = 0;
        for (int c = 0; c < NB; ++c) {
            int v = colt[c];
            colt[c] = run;
            run += v;
        }
        bstart[NB] = run;  // == N_EDGES
    }
    __syncthreads();
    for (int c = t; c < NB; c += 256) {
        int run = colt[c];
        bstart[c] = run;
#pragma unroll
        for (int rc = 0; rc < R_CH; ++rc) {
            cstart[rc * NB + c] = run;
            run += ctmp[rc * NB + c];
        }
    }
}

// ===========================================================================
// 2c) per-(block,bucket) exact offsets, in place in bhist
// ===========================================================================
__global__ __launch_bounds__(256) void scan_c_kernel(
    int* __restrict__ bhist, const int* __restrict__ cstart) {
    const int rc = blockIdx.x >> 3;
    const int cc = blockIdx.x & 7;
    const int c = cc * 256 + threadIdx.x;
    if (c >= NB) return;
    const int r0 = rc * ROWS_PER_CH;
    const int r1 = (r0 + ROWS_PER_CH < SC_BLOCKS) ? r0 + ROWS_PER_CH : SC_BLOCKS;
    int run = cstart[rc * NB + c];
    for (int r = r0; r < r1; ++r) {
        size_t i = (size_t)r * NB + c;
        int v = bhist[i];
        bhist[i] = run;
        run += v;
    }
}

// ===========================================================================
// 3) multisplit scatter: store[offset] = (local_dst<<19)|src
// ===========================================================================
__global__ __launch_bounds__(SC_THREADS) void mscatter_kernel(
    const int* __restrict__ src, const int* __restrict__ dst,
    const int* __restrict__ bhist, int* __restrict__ store) {
    __shared__ int hist[NB];
    __shared__ int basel[NB];
    const int t = threadIdx.x;
    for (int i = t; i < NB; i += SC_THREADS) hist[i] = 0;
    __syncthreads();
    const int base = blockIdx.x * SC_CHUNK;
    int bkt[SC_EPT], rnk[SC_EPT], pkd[SC_EPT];
#pragma unroll
    for (int k = 0; k < SC_EPT; ++k) {
        int e = base + k * SC_THREADS + t;
        bkt[k] = -1;
        if (e < N_EDGES) {
            int d = dst[e];
            int s = src[e];
            bkt[k] = d >> BK_BITS;
            pkd[k] = ((d & (BK_SIZE - 1)) << 19) | s;  // src < 2^19
            rnk[k] = atomicAdd(&hist[bkt[k]], 1);      // LDS atomic rank
        }
    }
    __syncthreads();
    const int* row = bhist + (size_t)blockIdx.x * NB;
    for (int i = t; i < NB; i += SC_THREADS) basel[i] = row[i];
    __syncthreads();
#pragma unroll
    for (int k = 0; k < SC_EPT; ++k) {
        if (bkt[k] >= 0) store[basel[bkt[k]] + rnk[k]] = pkd[k];
    }
}

// ===========================================================================
// 4) fused: per-bucket LDS aggregation + node transform + graph-embed partial
// ===========================================================================
__global__ __launch_bounds__(256) void baggr_fused_kernel(
    const int* __restrict__ bstart, const int* __restrict__ store,
    const float* __restrict__ x,
    const float* __restrict__ w_self, const float* __restrict__ b_self,
    const float* __restrict__ w_neigh, const float* __restrict__ b_neigh,
    float* __restrict__ h_out, float* __restrict__ hsum) {
    __shared__ float lagg[BK_SIZE * FEAT];  // 10 KB
    __shared__ float lcnt[BK_SIZE];         // 1 KB
    __shared__ float red[4][HID];
    const int t = threadIdx.x;
    const int b = blockIdx.x;
    const int j = t & 31;  // invariant under +256 strides
    float ws[FEAT], wn[FEAT];
#pragma unroll
    for (int k = 0; k < FEAT; ++k) {
        ws[k] = w_self[k * HID + j];
        wn[k] = w_neigh[k * HID + j];
    }
    const float bias = b_self[j] + b_neigh[j];

    for (int i = t; i < BK_SIZE * FEAT; i += 256) lagg[i] = 0.0f;
    lcnt[t] = 0.0f;  // blockDim == BK_SIZE == 256
    __syncthreads();

    const int s0 = bstart[b], e0 = bstart[b + 1];
    for (int o = s0 + t; o < e0; o += 256) {
        int v = store[o];  // coalesced
        int s = v & 0x7FFFF;
        int loc = v >> 19;  // 0..255
        const float2* xr = (const float2*)(x + (size_t)s * FEAT);
        float2 p0 = xr[0], p1 = xr[1], p2 = xr[2], p3 = xr[3], p4 = xr[4];
        float* la = lagg + loc * FEAT;
        atomicAdd(&la[0], p0.x); atomicAdd(&la[1], p0.y);
        atomicAdd(&la[2], p1.x); atomicAdd(&la[3], p1.y);
        atomicAdd(&la[4], p2.x); atomicAdd(&la[5], p2.y);
        atomicAdd(&la[6], p3.x); atomicAdd(&la[7], p3.y);
        atomicAdd(&la[8], p4.x); atomicAdd(&la[9], p4.y);
        atomicAdd(&lcnt[loc], 1.0f);
    }
    __syncthreads();

    const int node0 = b << BK_BITS;
    const int lim = (N_NODES - node0 < BK_SIZE) ? (N_NODES - node0) : BK_SIZE;
    float partial = 0.0f;
#pragma unroll 4
    for (int k = 0; k < 32; ++k) {
        int idx = (k << 8) + t;   // 0..8191 over (node_local, j)
        int nl = idx >> 5;
        if (nl < lim) {
            float inv = 1.0f / fmaxf(lcnt[nl], 1.0f);
            const float* xr = x + (size_t)(node0 + nl) * FEAT;
            const float* la = lagg + nl * FEAT;
            float acc = bias;
#pragma unroll
            for (int kk = 0; kk < FEAT; ++kk)
                acc += xr[kk] * ws[kk] + la[kk] * inv * wn[kk];
            acc = fmaxf(acc, 0.0f);
            h_out[(size_t)node0 * HID + idx] = acc;  // coalesced
            partial += acc;
        }
    }

    partial += __shfl_down(partial, 32);
    const int wave = t >> 6, lane = t & 63;
    if (lane < 32) red[wave][lane] = partial;
    __syncthreads();
    if (t < 32) {
        float s2 = red[0][t] + red[1][t] + red[2][t] + red[3][t];
        atomicAdd(&hsum[t], s2);
    }
}

// ===========================================================================
// 5) heads
// ===========================================================================
__global__ void head_kernel(const float* __restrict__ hsum,
                            const float* __restrict__ w_act,
                            const float* __restrict__ b_act,
                            const float* __restrict__ w_prim,
                            const float* __restrict__ b_prim,
                            float* __restrict__ out) {
    __shared__ float ge[HID];
    const int t = threadIdx.x;
    if (t < HID) {
        const float g = hsum[t] * (1.0f / (float)N_NODES);
        ge[t] = g;
        out[N_TOOLS + N_PRIM + t] = g;
    }
    __syncthreads();
    if (t < N_TOOLS) {
        float a = b_act[t];
#pragma unroll
        for (int jj = 0; jj < HID; ++jj) a += ge[jj] * w_act[jj * N_TOOLS + t];
        out[t] = a;
    }
    if (t >= 32 && t < 32 + N_PRIM) {
        const int p = t - 32;
        float a = b_prim[p];
#pragma unroll
        for (int jj = 0; jj < HID; ++jj) a += ge[jj] * w_prim[jj * N_PRIM + p];
        out[N_TOOLS + p] = a;
    }
}

// ===========================================================================
// fallback path (round-1), used only if ws_size is tiny
// ===========================================================================
__global__ void scatter_kernel(const int* __restrict__ src,
                               const int* __restrict__ dst,
                               const float* __restrict__ x,
                               float* __restrict__ agg,
                               float* __restrict__ cnt) {
    int e = blockIdx.x * blockDim.x + threadIdx.x;
    if (e >= N_EDGES) return;
    int s = src[e];
    int d = dst[e];
    const float* xr = x + (size_t)s * FEAT;
    float* ar = agg + (size_t)d * FEAT;
#pragma unroll
    for (int k = 0; k < FEAT; ++k) atomicAdd(&ar[k], xr[k]);
    atomicAdd(&cnt[d], 1.0f);
}

__global__ void node_kernel(const float* __restrict__ x,
                            const float* __restrict__ agg,
                            const float* __restrict__ cnt,
                            const float* __restrict__ w_self,
                            const float* __restrict__ b_self,
                            const float* __restrict__ w_neigh,
                            const float* __restrict__ b_neigh,
                            float* __restrict__ h_out,
                            float* __restrict__ hsum) {
    const int j = threadIdx.x & 31;
    float ws[FEAT], wn[FEAT];
#pragma unroll
    for (int k = 0; k < FEAT; ++k) {
        ws[k] = w_self[k * HID + j];
        wn[k] = w_neigh[k * HID + j];
    }
    const float bias = b_self[j] + b_neigh[j];
    const long total = (long)N_NODES * HID;
    const long stride = (long)gridDim.x * blockDim.x;
    float partial = 0.0f;
    for (long idx = (long)blockIdx.x * blockDim.x + threadIdx.x; idx < total;
         idx += stride) {
        const int i = (int)(idx >> 5);
        const float inv = 1.0f / fmaxf(cnt[i], 1.0f);
        const float* xr = x + (size_t)i * FEAT;
        const float* ar = agg + (size_t)i * FEAT;
        float acc = bias;
#pragma unroll
        for (int k = 0; k < FEAT; ++k) {
            acc += xr[k] * ws[k];
            acc += (ar[k] * inv) * wn[k];
        }
        acc = fmaxf(acc, 0.0f);
        h_out[idx] = acc;
        partial += acc;
    }
    partial += __shfl_down(partial, 32);
    __shared__ float red[4][HID];
    const int wave = threadIdx.x >> 6;
    const int lane = threadIdx.x & 63;
    if (lane < 32) red[wave][lane] = partial;
    __syncthreads();
    if (threadIdx.x < 32) {
        float s = red[0][threadIdx.x] + red[1][threadIdx.x] +
                  red[2][threadIdx.x] + red[3][threadIdx.x];
        atomicAdd(&hsum[threadIdx.x], s);
    }
}

extern "C" void kernel_launch(void* const* d_in, const int* in_sizes, int n_in,
                              void* d_out, int out_size, void* d_ws,
                              size_t ws_size, hipStream_t stream) {
    const float* x       = (const float*)d_in[0];
    const int*   ei      = (const int*)d_in[1];
    const float* w_self  = (const float*)d_in[2];
    const float* b_self  = (const float*)d_in[3];
    const float* w_neigh = (const float*)d_in[4];
    const float* b_neigh = (const float*)d_in[5];
    const float* w_act   = (const float*)d_in[6];
    const float* b_act   = (const float*)d_in[7];
    const float* w_prim  = (const float*)d_in[8];
    const float* b_prim  = (const float*)d_in[9];
    float* out = (float*)d_out;
    const int* src = ei;
    const int* dst = ei + N_EDGES;

    // ws layout (4B elems):
    //   bhist [SC_BLOCKS*NB] | ctmp [R_CH*NB] | cstart [R_CH*NB]
    //   | bstart [NB+1] | store [E] | hsum [HID]
    const size_t n_bhist = (size_t)SC_BLOCKS * NB;
    const size_t n_ctmp  = (size_t)R_CH * NB;
    const size_t n_bst   = NB + 1;
    const size_t need =
        (n_bhist + 2 * n_ctmp + n_bst + (size_t)N_EDGES + HID) * 4;

    if (ws_size >= need) {
        int*   bhist  = (int*)d_ws;
        int*   ctmp   = bhist + n_bhist;
        int*   cstart = ctmp + n_ctmp;
        int*   bstart = cstart + n_ctmp;
        int*   store  = bstart + n_bst;
        float* hsum   = (float*)(store + N_EDGES);

        hipMemsetAsync(hsum, 0, HID * sizeof(float), stream);

        bhist_kernel<<<SC_BLOCKS, SC_THREADS, 0, stream>>>(dst, bhist);
        scan_a_kernel<<<64, 256, 0, stream>>>(bhist, ctmp);
        scan_b_kernel<<<1, 256, 0, stream>>>(ctmp, bstart, cstart);
        scan_c_kernel<<<64, 256, 0, stream>>>(bhist, cstart);
        mscatter_kernel<<<SC_BLOCKS, SC_THREADS, 0, stream>>>(src, dst, bhist,
                                                              store);
        baggr_fused_kernel<<<NB, 256, 0, stream>>>(
            bstart, store, x, w_self, b_self, w_neigh, b_neigh,
            out + (N_TOOLS + N_PRIM + HID), hsum);
        head_kernel<<<1, 64, 0, stream>>>(hsum, w_act, b_act, w_prim, b_prim,
                                          out);
    } else {
        float* agg  = (float*)d_ws;
        float* cnt  = agg + (size_t)N_NODES * FEAT;
        float* hsum = cnt + N_NODES;
        const size_t zero_bytes =
            ((size_t)N_NODES * FEAT + N_NODES + HID) * sizeof(float);
        hipMemsetAsync(d_ws, 0, zero_bytes, stream);

        scatter_kernel<<<(N_EDGES + 255) / 256, 256, 0, stream>>>(src, dst, x,
                                                                  agg, cnt);
        node_kernel<<<4096, 256, 0, stream>>>(
            x, agg, cnt, w_self, b_self, w_neigh, b_neigh,
            out + (N_TOOLS + N_PRIM + HID), hsum);
        head_kernel<<<1, 64, 0, stream>>>(hsum, w_act, b_act, w_prim, b_prim,
                                          out);
    }
}